// Round 4
// baseline (667.736 us; speedup 1.0000x reference)
//
#include <hip/hip_runtime.h>
#include <hip/hip_bf16.h>

typedef __attribute__((ext_vector_type(8))) short short8;
typedef __attribute__((ext_vector_type(4))) float f32x4;
typedef __attribute__((ext_vector_type(16))) float f32x16;

#define LRELU_SLOPE 0.2f
#define ACT_GAIN 1.41421356237309515f
#define WG_RGB 0.04419417382415922f   // 1/sqrt(512)

__device__ __forceinline__ void glds16(const short* g, short* l) {
    __builtin_amdgcn_global_load_lds(
        (const __attribute__((address_space(1))) unsigned int*)g,
        (__attribute__((address_space(3))) unsigned int*)l, 16, 0, 0);
}

// ---------------- P0: zero Ypad border + init img to rgb_b
__global__ void k_init(__hip_bfloat16* __restrict__ Ypad,
                       const float* __restrict__ rgb_b, float* __restrict__ img) {
    int blk = blockIdx.x, tid = threadIdx.x;
    if (blk < 1040) {                       // border: 4160 slots, 4 per block
        int gslot = blk*4 + (tid >> 6);
        int b = gslot / 260;
        int cell = gslot - b*260;
        int h, w;
        if (cell < 66)       { h = 0;          w = cell; }
        else if (cell < 132) { h = 65;         w = cell - 66; }
        else if (cell < 196) { h = cell - 131; w = 0; }
        else                 { h = cell - 195; w = 65; }
        short8 z = {};
        *(short8*)((short*)Ypad + (((b*66 + h)*66) + w)*512 + (tid & 63)*8) = z;
    } else {                                // img init: 48 blocks x 4 f32x4
        int blk2 = blk - 1040;
        #pragma unroll
        for (int j = 0; j < 4; ++j) {
            int f4 = blk2*1024 + j*256 + tid;   // 0..49151 (f32x4 units)
            int b3 = f4 >> 10;
            int o3 = b3 % 3;
            float v = rgb_b[o3];
            f32x4 vv = {v, v, v, v};
            *(f32x4*)(img + f4*4) = vv;
        }
    }
}

// ---------------- P1: styles
__global__ void k_styles(const float* __restrict__ wsin,
                         const float* __restrict__ caw, const float* __restrict__ cab,
                         const float* __restrict__ raw_, const float* __restrict__ rab,
                         float* __restrict__ sbuf, float* __restrict__ s2buf) {
    int b = blockIdx.x, which = blockIdx.y;
    int tid = threadIdx.x, lane = tid & 63, wv = tid >> 6;
    const float* aw = which ? raw_ : caw;
    const float* ab = which ? rab : cab;
    float scale = which ? WG_RGB : 1.0f;
    float* op = which ? s2buf : sbuf;
    __shared__ float wsv[512];
    wsv[tid]       = wsin[(b*2 + which)*512 + tid];
    wsv[tid + 256] = wsin[(b*2 + which)*512 + tid + 256];
    __syncthreads();
    for (int c = wv; c < 512; c += 4) {
        float p = 0.f;
        #pragma unroll
        for (int kk = 0; kk < 8; ++kk)
            p += aw[c*512 + kk*64 + lane] * wsv[kk*64 + lane];
        #pragma unroll
        for (int off = 32; off; off >>= 1) p += __shfl_down(p, off, 64);
        if (lane == 0) op[b*512 + c] = (p + ab[c]) * scale;
    }
}

// ---------------- P2: w2sum + Abf pack
__global__ __launch_bounds__(256) void k_prepw(const float* __restrict__ conv_w,
                        float* __restrict__ w2sum, __hip_bfloat16* __restrict__ Abf) {
    int o = blockIdx.x, tid = threadIdx.x;
    __shared__ float wrow[4608];
    const f32x4* src = (const f32x4*)(conv_w + o*4608);
    #pragma unroll
    for (int r = 0; r < 5; ++r) {
        int idx = tid + (r << 8);
        if (idx < 1152) *(f32x4*)&wrow[idx*4] = src[idx];
    }
    __syncthreads();
    #pragma unroll
    for (int j = 0; j < 2; ++j) {
        int c = tid + (j << 8);
        float sum = 0.f;
        #pragma unroll
        for (int t = 0; t < 9; ++t) {
            float v = wrow[c*9 + t];
            sum += v*v;
            Abf[(t*512 + o)*512 + c] = __float2bfloat16(v);
        }
        w2sum[o*512 + c] = sum;
    }
}

// ---------------- P3: dcoef + rgbc
__global__ __launch_bounds__(256) void k_dcoef(const float* __restrict__ sbuf,
                                               const float* __restrict__ w2sum,
                                               const float* __restrict__ s2buf,
                                               const float* __restrict__ rgb_w,
                                               float* __restrict__ dcoef,
                                               float* __restrict__ rgbc) {
    int gw = blockIdx.x*4 + (threadIdx.x >> 6);
    int lane = threadIdx.x & 63;
    int b = gw >> 9, o = gw & 511;
    float acc = 0.f;
    #pragma unroll
    for (int i = 0; i < 8; ++i) {
        int c = (i << 6) + lane;
        float sv = sbuf[(b << 9) + c];
        acc += sv*sv*w2sum[(o << 9) + c];
    }
    #pragma unroll
    for (int off = 32; off; off >>= 1) acc += __shfl_down(acc, off, 64);
    if (lane == 0) dcoef[(b << 9) + o] = rsqrtf(acc + 1e-8f);
    if (blockIdx.x < 96) {
        int flat = blockIdx.x*256 + threadIdx.x;
        int bb = flat / 1536;
        int r  = flat - bb*1536;
        int c  = r & 511;
        rgbc[flat] = rgb_w[r] * s2buf[bb*512 + c];
    }
}

// ---------------- P4: Ypad interior
__global__ void k_ypad(const float* __restrict__ cst, const float* __restrict__ sbuf,
                       __hip_bfloat16* __restrict__ Ypad) {
    int b = blockIdx.x >> 6, h = blockIdx.x & 63, tid = threadIdx.x;
    __shared__ float tile[64][65];
    for (int cc = 0; cc < 8; ++cc) {
        int c0 = cc << 6;
        #pragma unroll
        for (int it = 0; it < 16; ++it) {
            int cl = (it << 2) + (tid >> 6);
            int w = tid & 63;
            tile[cl][w] = cst[(c0 + cl)*4096 + (h << 6) + w];
        }
        __syncthreads();
        #pragma unroll
        for (int it = 0; it < 16; ++it) {
            int flat = (it << 8) + tid;
            int w = flat >> 6, cl = flat & 63;
            float v = sbuf[(b << 9) + c0 + cl] * tile[cl][w];
            Ypad[(((b*66 + h + 1)*66) + (w + 1))*512 + c0 + cl] = __float2bfloat16(v);
        }
        __syncthreads();
    }
}

// ---------------- main conv GEMM: 256-thread / 4-wave blocks, 256x128 tile,
// 2 independent blocks per CU (decoupled barriers -> MFMA/LDS cross-block
// overlap), K16 phases (288), wave tile 128x64 (intensity 0.75 reads/MFMA).
// A: 4-slot x 8KB ring, staged distance-3, published by end-of-phase vmcnt(2).
// B: single 12KB buffer, staged at tap0 behind an in-phase counted barrier.
// Swizzle: x1(v)=((v>>2)^(v>>3))&1 on 2-slot-per-row layout — uniform
// 2 lanes/bank-group per 16-lane quarter (fixes R3's 2.8e7 conflicts).
__global__ __launch_bounds__(256, 2) void conv_gemm(
    const short* __restrict__ Abf,   // [9][512][512] bf16
    const short* __restrict__ Ypad,  // [16][66][66][512] bf16
    const float* __restrict__ dcoef, // [16][512]
    const float* __restrict__ noise, // [4096]
    const float* __restrict__ nstr,  // [1]
    const float* __restrict__ bias,  // [512]
    const float* __restrict__ rgbc,  // [16][3][512]
    float* __restrict__ xout,        // [16][512][4096]
    float* __restrict__ img)         // [16][3][4096], pre-init to rgb_b
{
    __shared__ short SH[22528];       // 45056B: Aring 32KB + Bbuf 12KB
    short* Aring = SH;                // 4 slots x 4096 shorts ([256 row][16c] swz)
    short* Bbuf  = SH + 16384;        // 768 slots ([264 pos][16c] swz + pad)
    float (*red)[3][2] = (float (*)[3][2])SH;   // post-loop overlay on Aring

    int tid = threadIdx.x, lane = tid & 63, wv = tid >> 6;   // wv 0..3
    int wr = wv >> 1, wc = wv & 1;    // wave tile (wr*128, wc*64)
    int ml32 = lane & 31, hi = lane >> 5;

    int blk = blockIdx.x;
    int xcd = blk & 7, idx = blk >> 3;
    int v = xcd * 128 + idx;          // bijective: 1024 blocks, 128 per XCD
    int mblk = v & 1, nblk = v >> 1;  // nblk 0..511
    int b = nblk >> 5;
    int n0 = (nblk & 31) << 7;        // 128 hw per block
    int h0 = n0 >> 6;                 // top padded row of 4-row halo window
    int o0 = mblk << 8;

    // ---- B staging: 768 slots = 3 rounds x 256 (264 real pos, tail padded)
    int bgofs[3];
    #pragma unroll
    for (int r = 0; r < 3; ++r) {
        int s = tid + (r << 8);
        int pos = s >> 1; if (pos > 263) pos = 263;   // pad slots: clamp src
        int q = (s & 1) ^ (((pos >> 2) ^ (pos >> 3)) & 1);
        int hl = pos / 66, ww = pos - hl * 66;
        bgofs[r] = (((b*66 + h0 + hl)*66) + ww)*512 + q*8;
    }
    // ---- A staging: 512 slots = 2 rounds x 256 (256 rows x 16c)
    int agofs[2];
    #pragma unroll
    for (int r = 0; r < 2; ++r) {
        int s = tid + (r << 8);
        int row = s >> 1;
        int q = (s & 1) ^ (((row >> 2) ^ (row >> 3)) & 1);
        agofs[r] = ((o0 + row) << 9) + q*8;
    }
    // ---- frag read addr precompute (A rows; swizzled 16B half select)
    int aro[4];
    #pragma unroll
    for (int mi = 0; mi < 4; ++mi) {
        int row = wr*128 + mi*32 + ml32;
        aro[mi] = row*16 + ((hi ^ (((row >> 2) ^ (row >> 3)) & 1)) << 3);
    }
    int pb0 = wc*66 + ml32;

    short* AW = Aring + wv*512;       // wave-uniform A write base
    short* BW = Bbuf + wv*512;        // wave-uniform B write base

    f32x16 acc[4][2] = {};
    short8 fa[2][4], fb[2][2];

    // ---- prologue: A slots 0,1,2 (taps 0,1,2 of chunk0)
    #pragma unroll
    for (int t = 0; t < 3; ++t) {
        glds16(Abf + (t << 18) + agofs[0], AW + t*4096);
        glds16(Abf + (t << 18) + agofs[1], AW + t*4096 + 2048);
    }
    asm volatile("s_waitcnt vmcnt(0)" ::: "memory");
    __builtin_amdgcn_s_barrier();

#define FRAGRD(SET, SLOT, TAPX)                                             \
    { _Pragma("unroll")                                                     \
      for (int mi = 0; mi < 4; ++mi)                                        \
          fa[SET][mi] = *(const short8*)(Aring + (SLOT)*4096 + aro[mi]);    \
      _Pragma("unroll")                                                     \
      for (int ni = 0; ni < 2; ++ni) {                                      \
          int p_ = pb0 + ((TAPX)/3)*66 + ((TAPX)%3) + ni*32;                \
          int jx = (hi ^ (((p_ >> 2) ^ (p_ >> 3)) & 1)) << 3;               \
          fb[SET][ni] = *(const short8*)(Bbuf + p_*16 + jx); } }

#define MMCL(SET)                                                           \
    __builtin_amdgcn_s_setprio(1);                                          \
    _Pragma("unroll")                                                       \
    for (int mi = 0; mi < 4; ++mi)                                          \
        _Pragma("unroll")                                                   \
        for (int ni = 0; ni < 2; ++ni)                                      \
            acc[mi][ni] = __builtin_amdgcn_mfma_f32_32x32x16_bf16(          \
                fa[SET][mi], fb[SET][ni], acc[mi][ni], 0, 0, 0);            \
    __builtin_amdgcn_s_setprio(0);

#define PHASE(TAP, CUR, C0, C0N, RB)                                        \
    {                                                                       \
        int rr  = ((RB) + (TAP)) & 3;                                       \
        int rrN = ((RB) + (TAP) + 1) & 3;                                   \
        int rw  = ((RB) + (TAP) + 3) & 3;                                   \
        constexpr int TAPN = ((TAP) + 1) % 9;                               \
        constexpr int TAPP = ((TAP) < 6) ? (TAP) + 3 : (TAP) - 6;           \
        constexpr int NXT = (CUR) ^ 1;                                      \
        if ((TAP) == 0) {                                                   \
            glds16(Ypad + bgofs[0] + (C0), BW);                             \
            glds16(Ypad + bgofs[1] + (C0), BW + 2048);                      \
            glds16(Ypad + bgofs[2] + (C0), BW + 4096);                      \
        }                                                                   \
        { const short* asrc_ = Abf + (TAPP << 18) + (((TAP) < 6) ? (C0) : (C0N)); \
          glds16(asrc_ + agofs[0], AW + rw*4096);                           \
          glds16(asrc_ + agofs[1], AW + rw*4096 + 2048); }                  \
        if ((TAP) == 0) {                                                   \
            asm volatile("s_waitcnt vmcnt(2)" ::: "memory");                \
            __builtin_amdgcn_s_barrier();                                   \
            FRAGRD(CUR, rr, 0)                                              \
        }                                                                   \
        if ((TAP) < 8) { FRAGRD(NXT, rrN, TAPN) }                           \
        __builtin_amdgcn_sched_barrier(0);                                  \
        MMCL(CUR)                                                           \
        asm volatile("s_waitcnt vmcnt(2)" ::: "memory");                    \
        __builtin_amdgcn_s_barrier();                                       \
    }

#define CHUNK9(PAR, C0, C0N, RB)                                            \
    PHASE(0, ((0+(PAR))&1), C0, C0N, RB) PHASE(1, ((1+(PAR))&1), C0, C0N, RB) \
    PHASE(2, ((2+(PAR))&1), C0, C0N, RB) PHASE(3, ((3+(PAR))&1), C0, C0N, RB) \
    PHASE(4, ((4+(PAR))&1), C0, C0N, RB) PHASE(5, ((5+(PAR))&1), C0, C0N, RB) \
    PHASE(6, ((6+(PAR))&1), C0, C0N, RB) PHASE(7, ((7+(PAR))&1), C0, C0N, RB) \
    PHASE(8, ((8+(PAR))&1), C0, C0N, RB)

    for (int cc = 0; cc < 16; ++cc) {
        int c0e = cc << 5;                 // even chunk (c16=2cc) channel base
        int rbe = (cc << 1) & 3;           // ring base = c16 % 4
        CHUNK9(0, c0e, c0e + 16, rbe)
        int c0o = c0e + 16;                // odd chunk c16=2cc+1
        int c0no = (c0e + 32) & 511;       // wraps on last chunk (dummy-safe)
        CHUNK9(1, c0o, c0no, (rbe + 1) & 3)
    }
#undef PHASE
#undef CHUNK9
#undef FRAGRD
#undef MMCL

    // drain in-flight ring writes before overlaying red on Aring
    asm volatile("s_waitcnt vmcnt(0)" ::: "memory");
    __builtin_amdgcn_s_barrier();

    // ---------------- epilogue: demod + noise + bias + lrelu + store + ToRGB
    // C/D layout (32x32): col = lane&31, row = (r&3) + 8*(r>>2) + 4*hi
    float ns = nstr[0];
    float pr0[2] = {0.f, 0.f}, pr1[2] = {0.f, 0.f}, pr2[2] = {0.f, 0.f};
    #pragma unroll
    for (int mi = 0; mi < 4; ++mi) {
        int ob = o0 + wr*128 + mi*32 + hi*4;
        f32x4 dc[4], bs[4], c0r[4], c1r[4], c2r[4];
        #pragma unroll
        for (int g = 0; g < 4; ++g) {
            dc[g]  = *(const f32x4*)(dcoef + (b << 9) + ob + g*8);
            bs[g]  = *(const f32x4*)(bias + ob + g*8);
            c0r[g] = *(const f32x4*)(rgbc + b*1536 + ob + g*8);
            c1r[g] = *(const f32x4*)(rgbc + b*1536 + 512 + ob + g*8);
            c2r[g] = *(const f32x4*)(rgbc + b*1536 + 1024 + ob + g*8);
        }
        #pragma unroll
        for (int ni = 0; ni < 2; ++ni) {
            int nl = wc*64 + ni*32 + ml32;
            int hw = n0 + nl;
            float nz = noise[hw] * ns;
            #pragma unroll
            for (int g = 0; g < 4; ++g)
                #pragma unroll
                for (int t = 0; t < 4; ++t) {
                    float vv = acc[mi][ni][g*4 + t] * dc[g][t] + nz + bs[g][t];
                    vv = (vv < 0.f ? LRELU_SLOPE*vv : vv) * ACT_GAIN;
                    xout[(((b << 9) + ob + g*8 + t) << 12) + hw] = vv;
                    pr0[ni] += vv * c0r[g][t];
                    pr1[ni] += vv * c1r[g][t];
                    pr2[ni] += vv * c2r[g][t];
                }
        }
    }
    #pragma unroll
    for (int ni = 0; ni < 2; ++ni) {
        pr0[ni] += __shfl_down(pr0[ni], 32, 64);
        pr1[ni] += __shfl_down(pr1[ni], 32, 64);
        pr2[ni] += __shfl_down(pr2[ni], 32, 64);
    }
    if (lane < 32) {
        #pragma unroll
        for (int ni = 0; ni < 2; ++ni) {
            int nl = wc*64 + ni*32 + ml32;
            red[nl][0][wr] = pr0[ni];
            red[nl][1][wr] = pr1[ni];
            red[nl][2][wr] = pr2[ni];
        }
    }
    __syncthreads();
    for (int p = tid; p < 384; p += 256) {
        int o3 = p >> 7, nl = p & 127;
        atomicAdd(img + ((b*3 + o3) << 12) + n0 + nl, red[nl][o3][0] + red[nl][o3][1]);
    }
}

extern "C" void kernel_launch(void* const* d_in, const int* in_sizes, int n_in,
                              void* d_out, int out_size, void* d_ws, size_t ws_size,
                              hipStream_t stream) {
    (void)in_sizes; (void)n_in; (void)out_size; (void)ws_size;
    const float* wsin   = (const float*)d_in[0];   // [16][2][512]
    const float* cst    = (const float*)d_in[1];   // [512][64][64]
    const float* conv_w = (const float*)d_in[2];   // [512][512][3][3]
    const float* conv_b = (const float*)d_in[3];   // [512]
    const float* caw    = (const float*)d_in[4];   // [512][512]
    const float* cab    = (const float*)d_in[5];   // [512]
    const float* noise  = (const float*)d_in[6];   // [64][64]
    const float* nstr   = (const float*)d_in[7];   // [1]
    const float* rgb_w  = (const float*)d_in[8];   // [3][512][1][1]
    const float* rgb_b  = (const float*)d_in[9];   // [3]
    const float* raw_   = (const float*)d_in[10];  // [512][512]
    const float* rab    = (const float*)d_in[11];  // [512]

    char* wsb = (char*)d_ws;
    float* sbuf   = (float*)(wsb + 0);         // 16*512 f32
    float* s2buf  = (float*)(wsb + 32768);     // 16*512 f32
    float* dcoef  = (float*)(wsb + 65536);     // 16*512 f32
    float* rgbc   = (float*)(wsb + 98304);     // 16*3*512 f32
    float* w2sum  = (float*)(wsb + 196608);    // 512*512 f32 ([o][c])
    __hip_bfloat16* Abf  = (__hip_bfloat16*)(wsb + 1245184);  // 9*512*512 bf16
    __hip_bfloat16* Ypad = (__hip_bfloat16*)(wsb + 5963776);  // 16*66*66*512 bf16

    float* xout = (float*)d_out;               // [16][512][4096]
    float* img  = xout + 33554432;             // [16][3][4096]

    k_init<<<1088, 256, 0, stream>>>(Ypad, rgb_b, img);
    k_styles<<<dim3(16, 2), 256, 0, stream>>>(wsin, caw, cab, raw_, rab, sbuf, s2buf);
    k_prepw<<<512, 256, 0, stream>>>(conv_w, w2sum, Abf);
    k_dcoef<<<2048, 256, 0, stream>>>(sbuf, w2sum, s2buf, rgb_w, dcoef, rgbc);
    k_ypad<<<1024, 256, 0, stream>>>(cst, sbuf, Ypad);
    conv_gemm<<<1024, 256, 0, stream>>>((const short*)Abf, (const short*)Ypad,
                                        dcoef, noise, nstr, conv_b, rgbc, xout, img);
}

// Round 6
// 572.926 us; speedup vs baseline: 1.1655x; 1.1655x over previous
//
#include <hip/hip_runtime.h>
#include <hip/hip_bf16.h>

typedef __attribute__((ext_vector_type(8))) short short8;
typedef __attribute__((ext_vector_type(4))) float f32x4;
typedef __attribute__((ext_vector_type(16))) float f32x16;

#define LRELU_SLOPE 0.2f
#define ACT_GAIN 1.41421356237309515f
#define WG_RGB 0.04419417382415922f   // 1/sqrt(512)
#define X1(v) ((((v) >> 2) ^ ((v) >> 3)) & 1)

__device__ __forceinline__ void glds16(const short* g, short* l) {
    __builtin_amdgcn_global_load_lds(
        (const __attribute__((address_space(1))) unsigned int*)g,
        (__attribute__((address_space(3))) unsigned int*)l, 16, 0, 0);
}

// ---------------- P0: zero Ypad border + init img to rgb_b
__global__ void k_init(__hip_bfloat16* __restrict__ Ypad,
                       const float* __restrict__ rgb_b, float* __restrict__ img) {
    int blk = blockIdx.x, tid = threadIdx.x;
    if (blk < 1040) {                       // border: 4160 slots, 4 per block
        int gslot = blk*4 + (tid >> 6);
        int b = gslot / 260;
        int cell = gslot - b*260;
        int h, w;
        if (cell < 66)       { h = 0;          w = cell; }
        else if (cell < 132) { h = 65;         w = cell - 66; }
        else if (cell < 196) { h = cell - 131; w = 0; }
        else                 { h = cell - 195; w = 65; }
        short8 z = {};
        *(short8*)((short*)Ypad + (((b*66 + h)*66) + w)*512 + (tid & 63)*8) = z;
    } else {                                // img init: 48 blocks x 4 f32x4
        int blk2 = blk - 1040;
        #pragma unroll
        for (int j = 0; j < 4; ++j) {
            int f4 = blk2*1024 + j*256 + tid;
            int b3 = f4 >> 10;
            int o3 = b3 % 3;
            float v = rgb_b[o3];
            f32x4 vv = {v, v, v, v};
            *(f32x4*)(img + f4*4) = vv;
        }
    }
}

// ---------------- P1: styles
__global__ void k_styles(const float* __restrict__ wsin,
                         const float* __restrict__ caw, const float* __restrict__ cab,
                         const float* __restrict__ raw_, const float* __restrict__ rab,
                         float* __restrict__ sbuf, float* __restrict__ s2buf) {
    int b = blockIdx.x, which = blockIdx.y;
    int tid = threadIdx.x, lane = tid & 63, wv = tid >> 6;
    const float* aw = which ? raw_ : caw;
    const float* ab = which ? rab : cab;
    float scale = which ? WG_RGB : 1.0f;
    float* op = which ? s2buf : sbuf;
    __shared__ float wsv[512];
    wsv[tid]       = wsin[(b*2 + which)*512 + tid];
    wsv[tid + 256] = wsin[(b*2 + which)*512 + tid + 256];
    __syncthreads();
    for (int c = wv; c < 512; c += 4) {
        float p = 0.f;
        #pragma unroll
        for (int kk = 0; kk < 8; ++kk)
            p += aw[c*512 + kk*64 + lane] * wsv[kk*64 + lane];
        #pragma unroll
        for (int off = 32; off; off >>= 1) p += __shfl_down(p, off, 64);
        if (lane == 0) op[b*512 + c] = (p + ab[c]) * scale;
    }
}

// ---------------- P2: w2sum + Abf pack
__global__ __launch_bounds__(256) void k_prepw(const float* __restrict__ conv_w,
                        float* __restrict__ w2sum, __hip_bfloat16* __restrict__ Abf) {
    int o = blockIdx.x, tid = threadIdx.x;
    __shared__ float wrow[4608];
    const f32x4* src = (const f32x4*)(conv_w + o*4608);
    #pragma unroll
    for (int r = 0; r < 5; ++r) {
        int idx = tid + (r << 8);
        if (idx < 1152) *(f32x4*)&wrow[idx*4] = src[idx];
    }
    __syncthreads();
    #pragma unroll
    for (int j = 0; j < 2; ++j) {
        int c = tid + (j << 8);
        float sum = 0.f;
        #pragma unroll
        for (int t = 0; t < 9; ++t) {
            float v = wrow[c*9 + t];
            sum += v*v;
            Abf[(t*512 + o)*512 + c] = __float2bfloat16(v);
        }
        w2sum[o*512 + c] = sum;
    }
}

// ---------------- P3: dcoef + rgbc
__global__ __launch_bounds__(256) void k_dcoef(const float* __restrict__ sbuf,
                                               const float* __restrict__ w2sum,
                                               const float* __restrict__ s2buf,
                                               const float* __restrict__ rgb_w,
                                               float* __restrict__ dcoef,
                                               float* __restrict__ rgbc) {
    int gw = blockIdx.x*4 + (threadIdx.x >> 6);
    int lane = threadIdx.x & 63;
    int b = gw >> 9, o = gw & 511;
    float acc = 0.f;
    #pragma unroll
    for (int i = 0; i < 8; ++i) {
        int c = (i << 6) + lane;
        float sv = sbuf[(b << 9) + c];
        acc += sv*sv*w2sum[(o << 9) + c];
    }
    #pragma unroll
    for (int off = 32; off; off >>= 1) acc += __shfl_down(acc, off, 64);
    if (lane == 0) dcoef[(b << 9) + o] = rsqrtf(acc + 1e-8f);
    if (blockIdx.x < 96) {
        int flat = blockIdx.x*256 + threadIdx.x;
        int bb = flat / 1536;
        int r  = flat - bb*1536;
        int c  = r & 511;
        rgbc[flat] = rgb_w[r] * s2buf[bb*512 + c];
    }
}

// ---------------- P4: Ypad interior
__global__ void k_ypad(const float* __restrict__ cst, const float* __restrict__ sbuf,
                       __hip_bfloat16* __restrict__ Ypad) {
    int b = blockIdx.x >> 6, h = blockIdx.x & 63, tid = threadIdx.x;
    __shared__ float tile[64][65];
    for (int cc = 0; cc < 8; ++cc) {
        int c0 = cc << 6;
        #pragma unroll
        for (int it = 0; it < 16; ++it) {
            int cl = (it << 2) + (tid >> 6);
            int w = tid & 63;
            tile[cl][w] = cst[(c0 + cl)*4096 + (h << 6) + w];
        }
        __syncthreads();
        #pragma unroll
        for (int it = 0; it < 16; ++it) {
            int flat = (it << 8) + tid;
            int w = flat >> 6, cl = flat & 63;
            float v = sbuf[(b << 9) + c0 + cl] * tile[cl][w];
            Ypad[(((b*66 + h + 1)*66) + (w + 1))*512 + c0 + cl] = __float2bfloat16(v);
        }
        __syncthreads();
    }
}

// ---------------- main conv GEMM: R3 macro-structure (512 thr, 256x256 tile,
// K32 phases, 144 phases, A 4-slot ring dist-3, counted vmcnt) with R4's
// PROVEN conflict-free LDS geometry: 16c rows, 1-bit swizzle X1(row/pos).
// A: [4 slot][2 ks][256 row][16c] (64KB). B: [2 half][2 ks][416 pos][16c]
// (52KB, pos padded 396->416 so staging ks-boundary is wave-aligned).
// B staged 1 round/tap on taps 0-3 (retired by tap4, first read tap8).
// vmcnt ledger: per-phase issues {3,3,3,3,2,2,2,2,2} = VMP (retires all of
// phase T-1 -> A slot T+1 ready before read-ahead at T, B ready by tap4).
// [R5 resubmit: prior round's bench failed on the container broker, not the
// kernel — structure re-audited (barrier uniformity, ledger, red overlay).]
__global__ __launch_bounds__(512, 2) void conv_gemm(
    const short* __restrict__ Abf,   // [9][512][512] bf16
    const short* __restrict__ Ypad,  // [16][66][66][512] bf16
    const float* __restrict__ dcoef, // [16][512]
    const float* __restrict__ noise, // [4096]
    const float* __restrict__ nstr,  // [1]
    const float* __restrict__ bias,  // [512]
    const float* __restrict__ rgbc,  // [16][3][512]
    float* __restrict__ xout,        // [16][512][4096]
    float* __restrict__ img)         // [16][3][4096], pre-init to rgb_b
{
    __shared__ short SH[59392];       // 118784B: Aring 64KB + B 52KB
    short* Aring = SH;                // [4 slot][2 ks][256 row][16c]
    short* Bbuf  = SH + 32768;        // [2 half][2 ks][416 pos][16c]
    float (*red)[3][2] = (float (*)[3][2])SH;   // post-loop overlay

    int tid = threadIdx.x, lane = tid & 63, wv = tid >> 6;   // wv 0..7
    int wr = wv >> 2, wc = wv & 3;    // wave tile rows wr*128, cols wc*64
    int ml32 = lane & 31, hi = lane >> 5;

    int blk = blockIdx.x;
    int xcd = blk & 7, idx = blk >> 3;
    int v = xcd * 64 + idx;           // bijective: 512 blocks, 64 per XCD
    int mblk = v & 1, nblk = v >> 1;  // nblk 0..255
    int b = nblk >> 4;
    int hw0 = (nblk & 15) << 8;       // 256 hw per block
    int h0 = hw0 >> 6;                // top padded row of 6-row halo window
    int o0 = mblk << 8;

    // ---- B staging sources: slot j = ks*832 + pos*2 + half (pos padded to 416)
    int bsrc[3];
    #pragma unroll
    for (int r = 0; r < 3; ++r) {
        int j = tid + (r << 9);
        int ks = (j >= 832) ? 1 : 0;
        int pe = (j - ks*832) >> 1;
        int pos = pe > 395 ? 395 : pe;     // clamp pad slots (never read)
        int half = j & 1;
        int q = half ^ X1(pos);
        int hl = pos / 66, ww = pos - hl*66;
        bsrc[r] = (((b*66 + h0 + hl)*66) + ww)*512 + ks*16 + q*8;
    }
    int bsrc3;
    {
        int j = 1536 + wv*16 + (lane & 15);   // remainder: lane<16 of each wave
        int pe = (j - 832) >> 1;
        int pos = pe > 395 ? 395 : pe;
        int half = j & 1;
        int q = half ^ X1(pos);
        int hl = pos / 66, ww = pos - hl*66;
        bsrc3 = (((b*66 + h0 + hl)*66) + ww)*512 + 16 + q*8;   // ks=1
    }
    // ---- A staging sources: round r = ks; row = tid>>1, half = tid&1
    int agofs[2];
    #pragma unroll
    for (int r = 0; r < 2; ++r) {
        int row = tid >> 1, half = tid & 1;
        int q = half ^ X1(row);
        agofs[r] = ((o0 + row) << 9) + r*16 + q*8;
    }
    // ---- frag read precompute
    int aro[4];
    #pragma unroll
    for (int mi = 0; mi < 4; ++mi) {
        int row = wr*128 + mi*32 + ml32;
        aro[mi] = row*16 + ((hi ^ X1(row)) << 3);
    }
    int pb0 = wc*66 + ml32;
    const int BPA[9] = {0, 1, 2, 66, 67, 68, 132, 133, 134};

    short* AW = Aring + wv*512;       // wave-uniform A write base

    f32x16 acc[4][2] = {};
    short8 faA[4], fbA[2], faB[4], fbB[2];

    // ---- prologue: B chunk0 -> half0 (4 issues), A slots 0..2 (6 issues)
    #pragma unroll
    for (int r = 0; r < 3; ++r)
        glds16(Ypad + bsrc[r], Bbuf + wv*512 + r*4096);
    if ((lane & 63) < 16) glds16(Ypad + bsrc3, Bbuf + 12288 + wv*128);
    #pragma unroll
    for (int t = 0; t < 3; ++t) {
        glds16(Abf + (t << 18) + agofs[0], AW + t*8192);
        glds16(Abf + (t << 18) + agofs[1], AW + t*8192 + 4096);
    }
    asm volatile("s_waitcnt vmcnt(2)" ::: "memory");   // slot2 pair may fly
    __builtin_amdgcn_s_barrier();
    // preload faA/fbA: slot0, ks0, tap0, half0
    #pragma unroll
    for (int mi = 0; mi < 4; ++mi)
        faA[mi] = *(const short8*)(Aring + aro[mi]);
    #pragma unroll
    for (int ni = 0; ni < 2; ++ni) {
        int p_ = pb0 + ni*32;
        fbA[ni] = *(const short8*)(Bbuf + p_*16 + ((hi ^ X1(p_)) << 3));
    }

    constexpr int VMP[9] = {3, 3, 3, 3, 2, 2, 2, 2, 2};

#define MMCL(FA, FB)                                                        \
    __builtin_amdgcn_s_setprio(1);                                          \
    _Pragma("unroll")                                                       \
    for (int mi = 0; mi < 4; ++mi)                                          \
        _Pragma("unroll")                                                   \
        for (int ni = 0; ni < 2; ++ni)                                      \
            acc[mi][ni] = __builtin_amdgcn_mfma_f32_32x32x16_bf16(          \
                FA[mi], FB[ni], acc[mi][ni], 0, 0, 0);                      \
    __builtin_amdgcn_s_setprio(0);

#define PH(TAP)                                                             \
    {                                                                       \
        int rr  = (rb + (TAP)) & 3;                                         \
        int rrN = (rb + (TAP) + 1) & 3;                                     \
        int rw  = (rb + (TAP) + 3) & 3;                                     \
        constexpr int TAPN = ((TAP) + 1) % 9;                               \
        constexpr int TAPP = ((TAP) < 6) ? (TAP) + 3 : (TAP) - 6;           \
        /* ks1 frags of current phase */                                    \
        _Pragma("unroll")                                                   \
        for (int mi = 0; mi < 4; ++mi)                                      \
            faB[mi] = *(const short8*)(Aring + rr*8192 + 4096 + aro[mi]);   \
        _Pragma("unroll")                                                   \
        for (int ni = 0; ni < 2; ++ni) {                                    \
            int p_ = pb0 + BPA[(TAP)] + ni*32;                              \
            fbB[ni] = *(const short8*)(Bcur + 6656 + p_*16                  \
                                       + ((hi ^ X1(p_)) << 3));             \
        }                                                                   \
        /* glds prefetch: A pair for slot rw; B round for next chunk */     \
        { const short* asrc_ = Abf + (TAPP << 18) + (((TAP) < 6) ? c0 : c0n); \
          glds16(asrc_ + agofs[0], AW + rw*8192);                           \
          glds16(asrc_ + agofs[1], AW + rw*8192 + 4096); }                  \
        if ((TAP) < 3) glds16(Ypad + bsrc[(TAP)] + c0n, BWn + (TAP)*4096);  \
        if ((TAP) == 3) { if ((lane & 63) < 16)                             \
            glds16(Ypad + bsrc3 + c0n, BRm); }                              \
        __builtin_amdgcn_sched_barrier(0);                                  \
        MMCL(faA, fbA)                                                      \
        __builtin_amdgcn_sched_barrier(0);                                  \
        /* next-phase ks0 frags */                                          \
        { const short* BbN = ((TAP) == 8) ? Bnxt : Bcur;                    \
          _Pragma("unroll")                                                 \
          for (int mi = 0; mi < 4; ++mi)                                    \
              faA[mi] = *(const short8*)(Aring + rrN*8192 + aro[mi]);       \
          _Pragma("unroll")                                                 \
          for (int ni = 0; ni < 2; ++ni) {                                  \
              int p_ = pb0 + BPA[TAPN] + ni*32;                             \
              fbA[ni] = *(const short8*)(BbN + p_*16                        \
                                         + ((hi ^ X1(p_)) << 3));           \
          } }                                                               \
        __builtin_amdgcn_sched_barrier(0);                                  \
        MMCL(faB, fbB)                                                      \
        asm volatile("s_waitcnt vmcnt(%0)" :: "i"(VMP[(TAP)]) : "memory");  \
        __builtin_amdgcn_s_barrier();                                       \
    }

    for (int ch = 0; ch < 16; ++ch) {
        int c0 = ch << 5;
        int c0n = (c0 + 32) & 511;        // wraps on last chunk (dummy-safe)
        int rb = ch & 3;                   // (9*ch) mod 4
        int half = ch & 1;
        const short* Bcur = Bbuf + half*13312;
        const short* Bnxt = Bbuf + (half ^ 1)*13312;
        short* BWn = (short*)Bnxt + wv*512;
        short* BRm = (short*)Bnxt + 12288 + wv*128;
        PH(0) PH(1) PH(2) PH(3) PH(4) PH(5) PH(6) PH(7) PH(8)
    }
#undef PH
#undef MMCL

    // drain in-flight glds before overlaying red on Aring
    asm volatile("s_waitcnt vmcnt(0)" ::: "memory");
    __builtin_amdgcn_s_barrier();

    // ---------------- epilogue: demod + noise + bias + lrelu + store + ToRGB
    // C/D layout (32x32): col = lane&31, row = (r&3) + 8*(r>>2) + 4*hi
    float ns = nstr[0];
    float pr0[2] = {0.f, 0.f}, pr1[2] = {0.f, 0.f}, pr2[2] = {0.f, 0.f};
    #pragma unroll
    for (int mi = 0; mi < 4; ++mi) {
        int ob = o0 + wr*128 + mi*32 + hi*4;
        f32x4 dc[4], bs[4], c0r[4], c1r[4], c2r[4];
        #pragma unroll
        for (int g = 0; g < 4; ++g) {
            dc[g]  = *(const f32x4*)(dcoef + (b << 9) + ob + g*8);
            bs[g]  = *(const f32x4*)(bias + ob + g*8);
            c0r[g] = *(const f32x4*)(rgbc + b*1536 + ob + g*8);
            c1r[g] = *(const f32x4*)(rgbc + b*1536 + 512 + ob + g*8);
            c2r[g] = *(const f32x4*)(rgbc + b*1536 + 1024 + ob + g*8);
        }
        #pragma unroll
        for (int ni = 0; ni < 2; ++ni) {
            int nl = wc*64 + ni*32 + ml32;
            int hw = hw0 + nl;
            float nz = noise[hw] * ns;
            #pragma unroll
            for (int g = 0; g < 4; ++g)
                #pragma unroll
                for (int t = 0; t < 4; ++t) {
                    float vv = acc[mi][ni][g*4 + t] * dc[g][t] + nz + bs[g][t];
                    vv = (vv < 0.f ? LRELU_SLOPE*vv : vv) * ACT_GAIN;
                    xout[(((b << 9) + ob + g*8 + t) << 12) + hw] = vv;
                    pr0[ni] += vv * c0r[g][t];
                    pr1[ni] += vv * c1r[g][t];
                    pr2[ni] += vv * c2r[g][t];
                }
        }
    }
    #pragma unroll
    for (int ni = 0; ni < 2; ++ni) {
        pr0[ni] += __shfl_down(pr0[ni], 32, 64);
        pr1[ni] += __shfl_down(pr1[ni], 32, 64);
        pr2[ni] += __shfl_down(pr2[ni], 32, 64);
    }
    if (lane < 32) {
        #pragma unroll
        for (int ni = 0; ni < 2; ++ni) {
            int nl = wc*64 + ni*32 + ml32;
            red[nl][0][wr] = pr0[ni];
            red[nl][1][wr] = pr1[ni];
            red[nl][2][wr] = pr2[ni];
        }
    }
    __syncthreads();
    for (int p = tid; p < 768; p += 512) {
        int o3 = p >> 8, nl = p & 255;
        atomicAdd(img + ((b*3 + o3) << 12) + hw0 + nl, red[nl][o3][0] + red[nl][o3][1]);
    }
}

extern "C" void kernel_launch(void* const* d_in, const int* in_sizes, int n_in,
                              void* d_out, int out_size, void* d_ws, size_t ws_size,
                              hipStream_t stream) {
    (void)in_sizes; (void)n_in; (void)out_size; (void)ws_size;
    const float* wsin   = (const float*)d_in[0];   // [16][2][512]
    const float* cst    = (const float*)d_in[1];   // [512][64][64]
    const float* conv_w = (const float*)d_in[2];   // [512][512][3][3]
    const float* conv_b = (const float*)d_in[3];   // [512]
    const float* caw    = (const float*)d_in[4];   // [512][512]
    const float* cab    = (const float*)d_in[5];   // [512]
    const float* noise  = (const float*)d_in[6];   // [64][64]
    const float* nstr   = (const float*)d_in[7];   // [1]
    const float* rgb_w  = (const float*)d_in[8];   // [3][512][1][1]
    const float* rgb_b  = (const float*)d_in[9];   // [3]
    const float* raw_   = (const float*)d_in[10];  // [512][512]
    const float* rab    = (const float*)d_in[11];  // [512]

    char* wsb = (char*)d_ws;
    float* sbuf   = (float*)(wsb + 0);         // 16*512 f32
    float* s2buf  = (float*)(wsb + 32768);     // 16*512 f32
    float* dcoef  = (float*)(wsb + 65536);     // 16*512 f32
    float* rgbc   = (float*)(wsb + 98304);     // 16*3*512 f32
    float* w2sum  = (float*)(wsb + 196608);    // 512*512 f32 ([o][c])
    __hip_bfloat16* Abf  = (__hip_bfloat16*)(wsb + 1245184);  // 9*512*512 bf16
    __hip_bfloat16* Ypad = (__hip_bfloat16*)(wsb + 5963776);  // 16*66*66*512 bf16

    float* xout = (float*)d_out;               // [16][512][4096]
    float* img  = xout + 33554432;             // [16][3][4096]

    k_init<<<1088, 256, 0, stream>>>(Ypad, rgb_b, img);
    k_styles<<<dim3(16, 2), 256, 0, stream>>>(wsin, caw, cab, raw_, rab, sbuf, s2buf);
    k_prepw<<<512, 256, 0, stream>>>(conv_w, w2sum, Abf);
    k_dcoef<<<2048, 256, 0, stream>>>(sbuf, w2sum, s2buf, rgb_w, dcoef, rgbc);
    k_ypad<<<1024, 256, 0, stream>>>(cst, sbuf, Ypad);
    conv_gemm<<<512, 512, 0, stream>>>((const short*)Abf, (const short*)Ypad,
                                       dcoef, noise, nstr, conv_b, rgbc, xout, img);
}